// Round 7
// baseline (258.987 us; speedup 1.0000x reference)
//
#include <hip/hip_runtime.h>
#include <hip/hip_bf16.h>

// out[b,o,n] = sum_{k<19,c<64} x[b,c,neigh[n,k]] * W[o,k*64+c] + bias[o]
// B=4, N_VERTS=40962, K_RING=19, C=64. Storage: x,W,b,out fp32 (values
// bf16-representable), neigh int32. bf16 MFMA path near-exact (R4: 1.6e-2).
//
// R7: conv is barrier-free + LDS-free. W A-frags are contiguous 16B per lane
// -> loaded directly global->VGPR (L2-resident, 152 KB). Gather software-
// pipelined depth 2, W depth 1, ring loop fully unrolled (static stages).

#define NV   40962
#define KR   19
#define CIN  64
#define COUT 64
#define NB   4
#define NTILES 321   // ceil(NV/128)

typedef __bf16 bf16;
typedef __bf16 bf16x8 __attribute__((ext_vector_type(8)));
typedef float  floatx4 __attribute__((ext_vector_type(4)));

#define XT_ELEMS ((size_t)NB * NV * CIN)
#define WB_OFF   ((XT_ELEMS * 2 + 255) & ~(size_t)255)
#define WS_NEED  (WB_OFF + (size_t)COUT * KR * CIN * 2)

// ---------------------------------------------------------------------------
// Kernel 1: x (B,C,N) fp32 -> xt (B,N,64) bf16. fp32 LDS tile, stride 65
// (bank = (v+c)%32, conflict-free both phases). 8 chunks/vertex on write.
// ---------------------------------------------------------------------------
__global__ __launch_bounds__(256) void transpose_kernel(
    const float* __restrict__ x, bf16* __restrict__ xt)
{
    __shared__ float tile[64 * 65];
    const int b  = blockIdx.y;
    const int v0 = blockIdx.x * 64;
    const int t  = threadIdx.x;

    const int vl = t & 63;
    const int c0 = t >> 6;
    const int vg = min(v0 + vl, NV - 1);
    #pragma unroll
    for (int p = 0; p < 16; ++p) {
        int c = c0 * 16 + p;
        tile[vl * 65 + c] = x[((size_t)(b * CIN + c)) * NV + vg];
    }
    __syncthreads();

    const int v = t >> 2;
    const int q = t & 3;
    if (v0 + v < NV) {
        #pragma unroll
        for (int p = 0; p < 2; ++p) {
            int chunk = q + p * 4;       // 0..7 -> channels 0..63
            bf16x8 o;
            #pragma unroll
            for (int j = 0; j < 8; ++j)
                o[j] = (bf16)tile[v * 65 + chunk * 8 + j];
            *(bf16x8*)&xt[((size_t)(b * NV + v0 + v)) * 64 + chunk * 8] = o;
        }
    }
}

// ---------------------------------------------------------------------------
// Kernel 1b: W fp32 (64x1216) -> bf16 (152 KB, once)
// ---------------------------------------------------------------------------
__global__ __launch_bounds__(256) void convw_kernel(
    const float* __restrict__ W, bf16* __restrict__ Wb)
{
    int i = blockIdx.x * 256 + threadIdx.x;
    const int total4 = COUT * KR * CIN / 4;
    if (i < total4) {
        float4 v = ((const float4*)W)[i];
        bf16* p = Wb + (size_t)i * 4;
        p[0] = (bf16)v.x; p[1] = (bf16)v.y; p[2] = (bf16)v.z; p[3] = (bf16)v.w;
    }
}

// ---------------------------------------------------------------------------
// Kernel 2: barrier-free gather-GEMM, mfma_f32_16x16x32_bf16.
//   A = W (m=o), frag = 8 contiguous bf16 at row ot*16+l15, col r*64+kc*32+g*8
//   B = gathered x (n=vertex), frag = xt row halves at g*8 / 32+g*8
//   D: col(lane&15)=vertex, row((lane>>4)*4+reg)=o -> n-contig stores.
// Each wave owns 32 vertices, fully self-paced (no LDS, no __syncthreads).
// XCD swizzle: batch = (blockIdx&7)>>1 pins each batch to one XCD pair.
// ---------------------------------------------------------------------------
__global__ __launch_bounds__(256, 3) void conv_kernel(
    const int*   __restrict__ neigh,
    const bf16*  __restrict__ xt,
    const bf16*  __restrict__ Wb,     // (64, 1216) bf16
    const float* __restrict__ bias,   // (64,) fp32
    float*       __restrict__ out)    // (B, 64, NV) fp32
{
    const int i    = blockIdx.x;
    const int b    = (i & 7) >> 1;
    const int tile = (i >> 3) * 2 + (i & 1);
    if (tile >= NTILES) return;
    const int n0   = tile * 128;

    const int t    = threadIdx.x;
    const int wv   = t >> 6;
    const int lane = t & 63;
    const int l15  = lane & 15;
    const int g    = lane >> 4;

    int nn[2], ib[2];
    #pragma unroll
    for (int s = 0; s < 2; ++s) {
        nn[s] = n0 + wv * 32 + s * 16 + l15;
        ib[s] = min(nn[s], NV - 1) * KR;
    }

    // per-lane base pointers
    const bf16* xb = xt + (((size_t)b * NV) << 6) + g * 8;   // + (v<<6)
    const bf16* wp = Wb + (size_t)l15 * (KR * 64) + g * 8;   // + row*(KR*64)

    floatx4 acc[2][4];
    #pragma unroll
    for (int s = 0; s < 2; ++s)
        #pragma unroll
        for (int o = 0; o < 4; ++o)
            acc[s][o] = (floatx4){0.f, 0.f, 0.f, 0.f};

    // ---- software pipeline state
    bf16x8 xf[2][2][2];   // [stage][s][half]
    bf16x8 wf[4][2];      // current ring W frags [ot][kc]

    // preload gather rings 0,1 ; W ring 0
    #pragma unroll
    for (int pr = 0; pr < 2; ++pr) {
        #pragma unroll
        for (int s = 0; s < 2; ++s) {
            int v = neigh[ib[s] + pr];
            v = ((unsigned)v < (unsigned)NV) ? v : 0;
            const bf16* p = xb + ((size_t)v << 6);
            xf[pr][s][0] = *(const bf16x8*)(p);
            xf[pr][s][1] = *(const bf16x8*)(p + 32);
        }
    }
    #pragma unroll
    for (int ot = 0; ot < 4; ++ot)
        #pragma unroll
        for (int kc = 0; kc < 2; ++kc)
            wf[ot][kc] = *(const bf16x8*)
                (wp + (size_t)(ot * 16) * (KR * 64) + kc * 32);

    #pragma unroll
    for (int r = 0; r < KR; ++r) {
        const int st = r & 1;

        // snapshot this ring's operands (SSA renames; no copies emitted)
        bf16x8 c[2][2];
        #pragma unroll
        for (int s = 0; s < 2; ++s) {
            c[s][0] = xf[st][s][0];
            c[s][1] = xf[st][s][1];
        }
        bf16x8 w[4][2];
        #pragma unroll
        for (int ot = 0; ot < 4; ++ot) {
            w[ot][0] = wf[ot][0];
            w[ot][1] = wf[ot][1];
        }

        // issue gather for ring r+2 into the stage we just drained
        if (r + 2 < KR) {
            #pragma unroll
            for (int s = 0; s < 2; ++s) {
                int v = neigh[ib[s] + r + 2];
                v = ((unsigned)v < (unsigned)NV) ? v : 0;
                const bf16* p = xb + ((size_t)v << 6);
                xf[st][s][0] = *(const bf16x8*)(p);
                xf[st][s][1] = *(const bf16x8*)(p + 32);
            }
        }
        // issue W loads for ring r+1
        if (r + 1 < KR) {
            #pragma unroll
            for (int ot = 0; ot < 4; ++ot)
                #pragma unroll
                for (int kc = 0; kc < 2; ++kc)
                    wf[ot][kc] = *(const bf16x8*)
                        (wp + (size_t)(ot * 16) * (KR * 64) + (r + 1) * 64 + kc * 32);
        }

        // 16 MFMAs on snapshotted operands
        #pragma unroll
        for (int ot = 0; ot < 4; ++ot)
            #pragma unroll
            for (int kc = 0; kc < 2; ++kc)
                #pragma unroll
                for (int s = 0; s < 2; ++s)
                    acc[s][ot] = __builtin_amdgcn_mfma_f32_16x16x32_bf16(
                        w[ot][kc], c[s][kc], acc[s][ot], 0, 0, 0);
    }

    #pragma unroll
    for (int ot = 0; ot < 4; ++ot) {
        #pragma unroll
        for (int ii = 0; ii < 4; ++ii) {
            int o = ot * 16 + g * 4 + ii;
            float bv = bias[o];
            #pragma unroll
            for (int s = 0; s < 2; ++s) {
                if (nn[s] < NV) {
                    out[((size_t)(b * COUT + o)) * NV + nn[s]] =
                        acc[s][ot][ii] + bv;
                }
            }
        }
    }
}

// ---------------------------------------------------------------------------
// Fallback (no workspace): one block per (b,n); fp32 in/out.
// ---------------------------------------------------------------------------
__global__ __launch_bounds__(64) void fallback_kernel(
    const int*   __restrict__ neigh,
    const float* __restrict__ x,
    const float* __restrict__ W,
    const float* __restrict__ bias,
    float*       __restrict__ out)
{
    __shared__ float xg[KR * CIN];
    const int bn = blockIdx.x;
    const int b  = bn / NV;
    const int n  = bn % NV;
    const int t  = threadIdx.x;

    for (int k = t; k < KR * CIN; k += 64) {
        int r = k / CIN, c = k - r * CIN;
        int v = neigh[n * KR + r];
        v = ((unsigned)v < (unsigned)NV) ? v : 0;
        xg[k] = x[((size_t)(b * CIN + c)) * NV + v];
    }
    __syncthreads();

    float s = bias[t];
    const float* wrow = W + (size_t)t * (KR * CIN);
    for (int k = 0; k < KR * CIN; ++k) s += xg[k] * wrow[k];
    out[((size_t)(b * COUT + t)) * NV + n] = s;
}

// ---------------------------------------------------------------------------
extern "C" void kernel_launch(void* const* d_in, const int* in_sizes, int n_in,
                              void* d_out, int out_size, void* d_ws, size_t ws_size,
                              hipStream_t stream)
{
    const float* x     = (const float*)d_in[0];
    const int*   neigh = (const int*)d_in[1];
    const float* W     = (const float*)d_in[2];
    const float* bias  = (const float*)d_in[3];
    float* out = (float*)d_out;

    if (d_ws != nullptr && ws_size >= WS_NEED) {
        bf16* xt = (bf16*)d_ws;
        bf16* Wb = (bf16*)((char*)d_ws + WB_OFF);

        dim3 tgrid((NV + 63) / 64, NB);
        transpose_kernel<<<tgrid, 256, 0, stream>>>(x, xt);
        convw_kernel<<<(COUT * KR * CIN / 4 + 255) / 256, 256, 0, stream>>>(W, Wb);

        int nblk = 8 * ((NTILES + 1) / 2);          // 1288
        conv_kernel<<<nblk, 256, 0, stream>>>(neigh, xt, Wb, bias, out);
    } else {
        fallback_kernel<<<NB * NV, 64, 0, stream>>>(neigh, x, W, bias, out);
    }
}

// Round 9
// 169.525 us; speedup vs baseline: 1.5277x; 1.5277x over previous
//
#include <hip/hip_runtime.h>
#include <hip/hip_bf16.h>

// out[b,o,n] = sum_{k<19,c<64} x[b,c,neigh[n,k]] * W[o,k*64+c] + bias[o]
// B=4, N_VERTS=40962, K_RING=19, C=64. Storage: x,W,b,out fp32 (values
// bf16-representable), neigh int32. bf16 MFMA path near-exact (1.6e-2).
//
// R9 = R8 with the W-staging bug fixed: each thread stages 32B/ring (two
// bf16x8), not 16B split into mismapped 8B halves (R8 left half of Wlds
// uninitialized -> NaN).

#define NV   40962
#define KR   19
#define CIN  64
#define COUT 64
#define NB   4
#define NTILES 321   // ceil(NV/128)

typedef __bf16 bf16;
typedef __bf16 bf16x8 __attribute__((ext_vector_type(8)));
typedef float  floatx4 __attribute__((ext_vector_type(4)));

#define XT_ELEMS ((size_t)NB * NV * CIN)
#define WB_OFF   ((XT_ELEMS * 2 + 255) & ~(size_t)255)
#define WS_NEED  (WB_OFF + (size_t)COUT * KR * CIN * 2)

// ---------------------------------------------------------------------------
// Kernel 1: x (B,C,N) fp32 -> xt (B,N,64) bf16 (row per vertex = 128B line).
// ---------------------------------------------------------------------------
__global__ __launch_bounds__(256) void transpose_kernel(
    const float* __restrict__ x, bf16* __restrict__ xt)
{
    __shared__ float tile[64 * 65];
    const int b  = blockIdx.y;
    const int v0 = blockIdx.x * 64;
    const int t  = threadIdx.x;

    const int vl = t & 63;
    const int c0 = t >> 6;
    const int vg = min(v0 + vl, NV - 1);
    #pragma unroll
    for (int p = 0; p < 16; ++p) {
        int c = c0 * 16 + p;
        tile[vl * 65 + c] = x[((size_t)(b * CIN + c)) * NV + vg];
    }
    __syncthreads();

    const int v = t >> 2;
    const int q = t & 3;
    if (v0 + v < NV) {
        #pragma unroll
        for (int p = 0; p < 2; ++p) {
            int chunk = q + p * 4;
            bf16x8 o;
            #pragma unroll
            for (int j = 0; j < 8; ++j)
                o[j] = (bf16)tile[v * 65 + chunk * 8 + j];
            *(bf16x8*)&xt[((size_t)(b * NV + v0 + v)) * 64 + chunk * 8] = o;
        }
    }
}

// ---------------------------------------------------------------------------
// Kernel 1b: W fp32 (64x1216) -> bf16 (152 KB, once)
// ---------------------------------------------------------------------------
__global__ __launch_bounds__(256) void convw_kernel(
    const float* __restrict__ W, bf16* __restrict__ Wb)
{
    int i = blockIdx.x * 256 + threadIdx.x;
    const int total4 = COUT * KR * CIN / 4;
    if (i < total4) {
        float4 v = ((const float4*)W)[i];
        bf16* p = Wb + (size_t)i * 4;
        p[0] = (bf16)v.x; p[1] = (bf16)v.y; p[2] = (bf16)v.z; p[3] = (bf16)v.w;
    }
}

// ---------------------------------------------------------------------------
// Kernel 2: gather-GEMM, mfma_f32_16x16x32_bf16, ring-pair pipelined.
// W LDS layout: slot(ot,kc,g,l15) at elem ((ot*2+kc)*64 + g*16 + l15)*8
//  -> MFMA read for (ot,kc) is base + lane*16B : conflict-free, one addr reg.
// Staging: thread (row=t>>2, q=t&3) loads W[row, ring*64 + q*16 .. +15]
// (two bf16x8) -> slots (q>>1, (q&1)*2) and (q>>1, (q&1)*2+1). 512 slots,
// each written exactly once.
// ---------------------------------------------------------------------------
__global__ __launch_bounds__(256, 4) void conv_kernel(
    const int*   __restrict__ neigh,
    const bf16*  __restrict__ xt,
    const bf16*  __restrict__ Wb,     // (64, 1216) bf16
    const float* __restrict__ bias,   // (64,) fp32
    float*       __restrict__ out)    // (B, 64, NV) fp32
{
    __shared__ alignas(16) bf16 Wlds[2][2][4096];   // [stage][ring-in-pair]

    const int i    = blockIdx.x;
    const int b    = (i & 7) >> 1;                  // XCD pair -> batch
    const int tile = (i >> 3) * 2 + (i & 1);
    if (tile >= NTILES) return;
    const int n0   = tile * 128;

    const int t    = threadIdx.x;
    const int wv   = t >> 6;
    const int lane = t & 63;
    const int l15  = lane & 15;
    const int g    = lane >> 4;

    int nn[2], ib[2];
    #pragma unroll
    for (int s = 0; s < 2; ++s) {
        nn[s] = n0 + wv * 32 + s * 16 + l15;
        ib[s] = min(nn[s], NV - 1) * KR;
    }

    const bf16* xb = xt + (((size_t)b * NV) << 6) + g * 8;   // + (v<<6)

    // W staging decomposition: thread -> (row, quarter)
    const int srow = t >> 2;            // o row 0..63
    const int c4   = t & 3;             // 16-elem quarter of the 64-elem slice
    const int skc  = c4 >> 1;
    const int sg0  = (c4 & 1) * 2;
    const int sot  = srow >> 4, sl15 = srow & 15;
    const int sdst0 = ((sot * 2 + skc) * 64 + (sg0 + 0) * 16 + sl15) * 8;
    const int sdst1 = ((sot * 2 + skc) * 64 + (sg0 + 1) * 16 + sl15) * 8;
    const bf16* sw = Wb + (size_t)srow * (KR * 64) + c4 * 16;

    floatx4 acc[2][4];
    #pragma unroll
    for (int s = 0; s < 2; ++s)
        #pragma unroll
        for (int o = 0; o < 4; ++o)
            acc[s][o] = (floatx4){0.f, 0.f, 0.f, 0.f};

    bf16x8 xf[2][2][2];   // [ring-in-pair][s][half] : current pair
    bf16x8 xg[2][2][2];   // next pair

    // ---- prologue: stage pair 0 (rings 0,1) -> buf 0; gather rings 0,1
    #pragma unroll
    for (int j = 0; j < 2; ++j) {
        bf16x8 w0 = *(const bf16x8*)(sw + j * 64);
        bf16x8 w1 = *(const bf16x8*)(sw + j * 64 + 8);
        *(bf16x8*)(&Wlds[0][j][sdst0]) = w0;
        *(bf16x8*)(&Wlds[0][j][sdst1]) = w1;
        #pragma unroll
        for (int s = 0; s < 2; ++s) {
            int v = neigh[ib[s] + j];
            v = ((unsigned)v < (unsigned)NV) ? v : 0;
            const bf16* p = xb + ((size_t)v << 6);
            xf[j][s][0] = *(const bf16x8*)(p);
            xf[j][s][1] = *(const bf16x8*)(p + 32);
        }
    }
    __syncthreads();

    #pragma unroll
    for (int rp = 0; rp < 10; ++rp) {           // pairs: rings (2rp, 2rp+1)
        const int st = rp & 1;

        // ---- prefetch next pair: W -> buf st^1, gathers -> xg
        if (rp + 1 < 10) {
            #pragma unroll
            for (int j = 0; j < 2; ++j) {
                const int ring = 2 * (rp + 1) + j;
                if (ring < KR) {
                    bf16x8 w0 = *(const bf16x8*)(sw + ring * 64);
                    bf16x8 w1 = *(const bf16x8*)(sw + ring * 64 + 8);
                    *(bf16x8*)(&Wlds[st ^ 1][j][sdst0]) = w0;
                    *(bf16x8*)(&Wlds[st ^ 1][j][sdst1]) = w1;
                    #pragma unroll
                    for (int s = 0; s < 2; ++s) {
                        int v = neigh[ib[s] + ring];
                        v = ((unsigned)v < (unsigned)NV) ? v : 0;
                        const bf16* p = xb + ((size_t)v << 6);
                        xg[j][s][0] = *(const bf16x8*)(p);
                        xg[j][s][1] = *(const bf16x8*)(p + 32);
                    }
                }
            }
        }

        // ---- compute rings 2rp, 2rp+1 from buf st
        #pragma unroll
        for (int j = 0; j < 2; ++j) {
            const int ring = 2 * rp + j;
            if (ring < KR) {
                const bf16* wbase = &Wlds[st][j][lane * 8];
                #pragma unroll
                for (int ot = 0; ot < 4; ++ot) {
                    #pragma unroll
                    for (int kc = 0; kc < 2; ++kc) {
                        bf16x8 wf = *(const bf16x8*)(wbase + (ot * 2 + kc) * 512);
                        #pragma unroll
                        for (int s = 0; s < 2; ++s) {
                            acc[s][ot] = __builtin_amdgcn_mfma_f32_16x16x32_bf16(
                                wf, xf[j][s][kc], acc[s][ot], 0, 0, 0);
                        }
                    }
                }
            }
        }
        __syncthreads();

        // rotate gather pipeline (SSA-renamed under full unroll)
        #pragma unroll
        for (int j = 0; j < 2; ++j)
            #pragma unroll
            for (int s = 0; s < 2; ++s) {
                xf[j][s][0] = xg[j][s][0];
                xf[j][s][1] = xg[j][s][1];
            }
    }

    #pragma unroll
    for (int ot = 0; ot < 4; ++ot) {
        #pragma unroll
        for (int ii = 0; ii < 4; ++ii) {
            int o = ot * 16 + g * 4 + ii;
            float bv = bias[o];
            #pragma unroll
            for (int s = 0; s < 2; ++s) {
                if (nn[s] < NV) {
                    out[((size_t)(b * COUT + o)) * NV + nn[s]] =
                        acc[s][ot][ii] + bv;
                }
            }
        }
    }
}

// ---------------------------------------------------------------------------
// Fallback (no workspace): one block per (b,n); fp32 in/out.
// ---------------------------------------------------------------------------
__global__ __launch_bounds__(64) void fallback_kernel(
    const int*   __restrict__ neigh,
    const float* __restrict__ x,
    const float* __restrict__ W,
    const float* __restrict__ bias,
    float*       __restrict__ out)
{
    __shared__ float xg[KR * CIN];
    const int bn = blockIdx.x;
    const int b  = bn / NV;
    const int n  = bn % NV;
    const int t  = threadIdx.x;

    for (int k = t; k < KR * CIN; k += 64) {
        int r = k / CIN, c = k - r * CIN;
        int v = neigh[n * KR + r];
        v = ((unsigned)v < (unsigned)NV) ? v : 0;
        xg[k] = x[((size_t)(b * CIN + c)) * NV + v];
    }
    __syncthreads();

    float s = bias[t];
    const float* wrow = W + (size_t)t * (KR * CIN);
    for (int k = 0; k < KR * CIN; ++k) s += xg[k] * wrow[k];
    out[((size_t)(b * COUT + t)) * NV + n] = s;
}

// ---------------------------------------------------------------------------
extern "C" void kernel_launch(void* const* d_in, const int* in_sizes, int n_in,
                              void* d_out, int out_size, void* d_ws, size_t ws_size,
                              hipStream_t stream)
{
    const float* x     = (const float*)d_in[0];
    const int*   neigh = (const int*)d_in[1];
    const float* W     = (const float*)d_in[2];
    const float* bias  = (const float*)d_in[3];
    float* out = (float*)d_out;

    if (d_ws != nullptr && ws_size >= WS_NEED) {
        bf16* xt = (bf16*)d_ws;
        bf16* Wb = (bf16*)((char*)d_ws + WB_OFF);

        dim3 tgrid((NV + 63) / 64, NB);
        transpose_kernel<<<tgrid, 256, 0, stream>>>(x, xt);
        convw_kernel<<<(COUT * KR * CIN / 4 + 255) / 256, 256, 0, stream>>>(W, Wb);

        int nblk = 8 * ((NTILES + 1) / 2);          // 1288
        conv_kernel<<<nblk, 256, 0, stream>>>(neigh, xt, Wb, bias, out);
    } else {
        fallback_kernel<<<NB * NV, 64, 0, stream>>>(neigh, x, W, bias, out);
    }
}